// Round 1
// baseline (2698.364 us; speedup 1.0000x reference)
//
#include <hip/hip_runtime.h>

// ---------------- problem constants ----------------
#define B_     8
#define CIN    512
#define HFM    10
#define WFM    25
#define CF     64
#define NANCH  2784          // N
#define NM     2783          // N-1
#define D_     640           // CF*HFM
#define D2     1280
#define ALEN   77            // 5 + 72
#define M_     (B_*NANCH)    // 22272 rows (b,n)

// ---------------- GEMM tiling ----------------
#define BM 64
#define BN 64
#define BK 16

// ============ 1x1 conv: feat[b][f][h][w] = sum_c x[b][c][h][w]*w[f][c] + bias ============
__global__ __launch_bounds__(256) void conv_feat_k(const float* __restrict__ x,
    const float* __restrict__ w, const float* __restrict__ bias,
    float* __restrict__ feat)
{
    int t = blockIdx.x * 256 + threadIdx.x;
    if (t >= B_ * CF * HFM * WFM) return;
    int pos = t % (HFM * WFM);
    int f   = (t / (HFM * WFM)) % CF;
    int b   = t / (CF * HFM * WFM);
    const float* xp = x + (size_t)b * CIN * HFM * WFM + pos;
    const float* wp = w + (size_t)f * CIN;
    float s = bias[f];
#pragma unroll 4
    for (int c = 0; c < CIN; ++c)
        s += xp[(size_t)c * (HFM * WFM)] * wp[c];
    feat[t] = s;
}

// ============ gather: pf[b][n][f*10+h] = feat[b][f][h][cut_xs[n][h]] (0 if invalid) ============
__global__ __launch_bounds__(256) void gather_k(const float* __restrict__ feat,
    const int* __restrict__ cut_xs, const unsigned char* __restrict__ invalid,
    float* __restrict__ pf)
{
    long long t = (long long)blockIdx.x * 256 + threadIdx.x;
    if (t >= (long long)M_ * D_) return;
    int d = (int)(t % D_);
    int r = (int)(t / D_);          // b*N + n
    int n = r % NANCH;
    int b = r / NANCH;
    int f = d / HFM, h = d - f * HFM;
    int idx = n * HFM + h;
    float v = 0.f;
    if (!invalid[idx]) {
        int xs = cut_xs[idx];
        v = feat[((size_t)(b * CF + f) * HFM + h) * WFM + xs];
    }
    pf[t] = v;
}

// ============ scores GEMM: C[r][m] = pf[r][:]·attn_w[m][:] + attn_b[m]
//              scattered to attn_out[b][n][m + (m>=n)] (raw, pre-softmax) ============
__global__ __launch_bounds__(256) void scores_gemm_k(const float* __restrict__ pf,
    const float* __restrict__ attn_w, const float* __restrict__ attn_b,
    float* __restrict__ attn_out)
{
    __shared__ __align__(16) float As[BK][BM];
    __shared__ __align__(16) float Bs[BK][BN];
    const int t   = threadIdx.x;
    const int tx  = t & 15, ty = t >> 4;
    const int row0 = blockIdx.x * BM;
    const int col0 = blockIdx.y * BN;
    const int lrow = t >> 2;          // 0..63
    const int lkc  = (t & 3) << 2;    // 0,4,8,12
    const int brow = col0 + lrow;
    const float* aptr = pf + (size_t)(row0 + lrow) * D_ + lkc;
    const float* bptr = (brow < NM) ? (attn_w + (size_t)brow * D_ + lkc) : nullptr;
    float acc[4][4] = {};
    for (int k0 = 0; k0 < D_; k0 += BK) {
        float4 av = *(const float4*)(aptr + k0);
        float4 bv = bptr ? *(const float4*)(bptr + k0) : make_float4(0.f, 0.f, 0.f, 0.f);
        __syncthreads();
        As[lkc + 0][lrow] = av.x; As[lkc + 1][lrow] = av.y;
        As[lkc + 2][lrow] = av.z; As[lkc + 3][lrow] = av.w;
        Bs[lkc + 0][lrow] = bv.x; Bs[lkc + 1][lrow] = bv.y;
        Bs[lkc + 2][lrow] = bv.z; Bs[lkc + 3][lrow] = bv.w;
        __syncthreads();
#pragma unroll
        for (int k = 0; k < BK; ++k) {
            float4 a = *(const float4*)(&As[k][ty << 2]);
            float4 b = *(const float4*)(&Bs[k][tx << 2]);
            float aa[4] = {a.x, a.y, a.z, a.w};
            float bb[4] = {b.x, b.y, b.z, b.w};
#pragma unroll
            for (int i = 0; i < 4; ++i)
#pragma unroll
                for (int j = 0; j < 4; ++j)
                    acc[i][j] += aa[i] * bb[j];
        }
    }
#pragma unroll
    for (int i = 0; i < 4; ++i) {
        int r = row0 + (ty << 2) + i;
        int n = r % NANCH;
        float* orow = attn_out + (size_t)r * NANCH;
#pragma unroll
        for (int j = 0; j < 4; ++j) {
            int m = col0 + (tx << 2) + j;
            if (m < NM) {
                int col = m + (m >= n);
                orow[col] = acc[i][j] + attn_b[m];
            }
        }
    }
}

// ============ softmax over each attn row (2783 real entries; diagonal excluded, set 0) ============
__global__ __launch_bounds__(256) void softmax_k(float* __restrict__ attn)
{
    const int r = blockIdx.x;           // 0..M_-1
    const int n = r % NANCH;
    float* row = attn + (size_t)r * NANCH;
    const int t = threadIdx.x;
    __shared__ float red[4];

    float vals[11];
    int cnt = 0;
    float mx = -1e30f;
    for (int j = t; j < NANCH; j += 256) {
        float v = (j == n) ? -1e30f : row[j];
        vals[cnt++] = v;
        mx = fmaxf(mx, v);
    }
    for (int off = 32; off; off >>= 1) mx = fmaxf(mx, __shfl_down(mx, off));
    if ((t & 63) == 0) red[t >> 6] = mx;
    __syncthreads();
    mx = fmaxf(fmaxf(red[0], red[1]), fmaxf(red[2], red[3]));
    __syncthreads();

    float s = 0.f;
    for (int i = 0; i < cnt; ++i) {
        float e = __expf(vals[i] - mx);   // j==n: exp(-huge) -> 0
        vals[i] = e;
        s += e;
    }
    for (int off = 32; off; off >>= 1) s += __shfl_down(s, off);
    if ((t & 63) == 0) red[t >> 6] = s;
    __syncthreads();
    s = red[0] + red[1] + red[2] + red[3];
    float inv = 1.0f / s;
    cnt = 0;
    for (int j = t; j < NANCH; j += 256)
        row[j] = vals[cnt++] * inv;       // diagonal: 0 * inv = 0
}

// ============ att_feats GEMM: att_feats[b][n][d] = sum_j attn[b][n][j] * pf[b][j][d] ============
__global__ __launch_bounds__(256) void att_gemm_k(const float* __restrict__ attn,
    const float* __restrict__ pf, float* __restrict__ att_feats)
{
    __shared__ __align__(16) float As[BK][BM];
    __shared__ __align__(16) float Bs[BK][BN];
    const int t  = threadIdx.x;
    const int tx = t & 15, ty = t >> 4;
    const int b    = blockIdx.z;
    const int row0 = blockIdx.x * BM;   // n
    const int col0 = blockIdx.y * BN;   // d
    const int lrow = t >> 2;
    const int lkc  = (t & 3) << 2;
    const int kk   = t >> 4;            // 0..15
    const int cc   = (t & 15) << 2;     // 0..60
    const int arow = row0 + lrow;
    const bool aok = (arow < NANCH);
    const float* abase = attn + ((size_t)b * NANCH + arow) * NANCH + lkc;
    const float* bbase = pf + ((size_t)b * NANCH + kk) * D_ + col0 + cc;
    float acc[4][4] = {};
    for (int k0 = 0; k0 < NANCH; k0 += BK) {
        float4 av = aok ? *(const float4*)(abase + k0) : make_float4(0.f, 0.f, 0.f, 0.f);
        float4 bv = *(const float4*)(bbase + (size_t)k0 * D_);
        __syncthreads();
        As[lkc + 0][lrow] = av.x; As[lkc + 1][lrow] = av.y;
        As[lkc + 2][lrow] = av.z; As[lkc + 3][lrow] = av.w;
        *(float4*)(&Bs[kk][cc]) = bv;
        __syncthreads();
#pragma unroll
        for (int k = 0; k < BK; ++k) {
            float4 a = *(const float4*)(&As[k][ty << 2]);
            float4 bq = *(const float4*)(&Bs[k][tx << 2]);
            float aa[4] = {a.x, a.y, a.z, a.w};
            float bb[4] = {bq.x, bq.y, bq.z, bq.w};
#pragma unroll
            for (int i = 0; i < 4; ++i)
#pragma unroll
                for (int j = 0; j < 4; ++j)
                    acc[i][j] += aa[i] * bb[j];
        }
    }
#pragma unroll
    for (int i = 0; i < 4; ++i) {
        int nrow = row0 + (ty << 2) + i;
        if (nrow < NANCH) {
            float4 st = make_float4(acc[i][0], acc[i][1], acc[i][2], acc[i][3]);
            *(float4*)(att_feats + ((size_t)b * NANCH + nrow) * D_ + col0 + (tx << 2)) = st;
        }
    }
}

// ============ heads GEMM: cat = [att_feats | pf] (K=1280); 75 outputs = 2 cls + 73 reg.
//              Fused lanes epilogue: lanes[.,4]=reg0, lanes[.,4+q]=anchors[.,4+q]+reg_q (q>=1) ============
__global__ __launch_bounds__(256) void heads_gemm_k(const float* __restrict__ att_feats,
    const float* __restrict__ pf,
    const float* __restrict__ cls_w, const float* __restrict__ cls_b,
    const float* __restrict__ reg_w, const float* __restrict__ reg_b,
    const float* __restrict__ anchors,
    float* __restrict__ cls_out, float* __restrict__ lanes)
{
    __shared__ __align__(16) float As[BK][BM];
    __shared__ __align__(16) float Bs[BK][BN];
    const int t  = threadIdx.x;
    const int tx = t & 15, ty = t >> 4;
    const int row0 = blockIdx.x * BM;
    const int col0 = blockIdx.y * BN;   // output idx tile (0..74 valid)
    const int lrow = t >> 2;
    const int lkc  = (t & 3) << 2;
    const int o    = col0 + lrow;
    const float* wsrc = nullptr;
    if (o < 2)       wsrc = cls_w + (size_t)o * D2;
    else if (o < 75) wsrc = reg_w + (size_t)(o - 2) * D2;
    float acc[4][4] = {};
    for (int k0 = 0; k0 < D2; k0 += BK) {
        const float* asrc = (k0 < D_)
            ? (att_feats + (size_t)(row0 + lrow) * D_ + k0 + lkc)
            : (pf        + (size_t)(row0 + lrow) * D_ + (k0 - D_) + lkc);
        float4 av = *(const float4*)asrc;
        float4 bv = wsrc ? *(const float4*)(wsrc + k0 + lkc) : make_float4(0.f, 0.f, 0.f, 0.f);
        __syncthreads();
        As[lkc + 0][lrow] = av.x; As[lkc + 1][lrow] = av.y;
        As[lkc + 2][lrow] = av.z; As[lkc + 3][lrow] = av.w;
        Bs[lkc + 0][lrow] = bv.x; Bs[lkc + 1][lrow] = bv.y;
        Bs[lkc + 2][lrow] = bv.z; Bs[lkc + 3][lrow] = bv.w;
        __syncthreads();
#pragma unroll
        for (int k = 0; k < BK; ++k) {
            float4 a = *(const float4*)(&As[k][ty << 2]);
            float4 bq = *(const float4*)(&Bs[k][tx << 2]);
            float aa[4] = {a.x, a.y, a.z, a.w};
            float bb[4] = {bq.x, bq.y, bq.z, bq.w};
#pragma unroll
            for (int i = 0; i < 4; ++i)
#pragma unroll
                for (int j = 0; j < 4; ++j)
                    acc[i][j] += aa[i] * bb[j];
        }
    }
#pragma unroll
    for (int i = 0; i < 4; ++i) {
        int r = row0 + (ty << 2) + i;
        int n = r % NANCH;
#pragma unroll
        for (int j = 0; j < 4; ++j) {
            int oo = col0 + (tx << 2) + j;
            float v = acc[i][j];
            if (oo < 2) {
                cls_out[(size_t)r * 2 + oo] = v + cls_b[oo];
            } else if (oo < 75) {
                int q = oo - 2;
                int c = 4 + q;
                float res = v + reg_b[q];
                if (q > 0) res += anchors[(size_t)n * ALEN + c];
                lanes[(size_t)r * ALEN + c] = res;
            }
        }
    }
}

// ============ lanes cols 0..3 = anchors cols 0..3 ============
__global__ __launch_bounds__(256) void lanes_init_k(const float* __restrict__ anchors,
    float* __restrict__ lanes)
{
    int t = blockIdx.x * 256 + threadIdx.x;
    if (t >= M_ * 4) return;
    int c = t & 3;
    int r = t >> 2;
    int n = r % NANCH;
    lanes[(size_t)r * ALEN + c] = anchors[(size_t)n * ALEN + c];
}

extern "C" void kernel_launch(void* const* d_in, const int* in_sizes, int n_in,
                              void* d_out, int out_size, void* d_ws, size_t ws_size,
                              hipStream_t stream)
{
    (void)in_sizes; (void)n_in; (void)out_size; (void)ws_size;
    const float* x       = (const float*)d_in[0];
    const float* conv_w  = (const float*)d_in[1];
    const float* conv_b  = (const float*)d_in[2];
    const float* attn_w  = (const float*)d_in[3];
    const float* attn_b  = (const float*)d_in[4];
    const float* cls_w   = (const float*)d_in[5];
    const float* cls_b   = (const float*)d_in[6];
    const float* reg_w   = (const float*)d_in[7];
    const float* reg_b   = (const float*)d_in[8];
    const float* anchors = (const float*)d_in[9];
    const int*   cut_xs  = (const int*)d_in[10];
    const unsigned char* invalid = (const unsigned char*)d_in[11];

    float* out     = (float*)d_out;
    float* cls_out = out;                                   // 8*2784*2
    float* lanes   = out + (size_t)M_ * 2;                  // 8*2784*77
    float* attn    = out + (size_t)M_ * 2 + (size_t)M_ * ALEN; // 8*2784*2784

    float* feat      = (float*)d_ws;                        // 128,000 f32
    float* pf        = feat + (size_t)B_ * CF * HFM * WFM;  // 14,254,080 f32
    float* att_feats = pf + (size_t)M_ * D_;                // 14,254,080 f32

    conv_feat_k<<<(B_ * CF * HFM * WFM + 255) / 256, 256, 0, stream>>>(x, conv_w, conv_b, feat);
    gather_k<<<(int)(((long long)M_ * D_ + 255) / 256), 256, 0, stream>>>(feat, cut_xs, invalid, pf);
    scores_gemm_k<<<dim3(M_ / BM, (NM + BN - 1) / BN), 256, 0, stream>>>(pf, attn_w, attn_b, attn);
    softmax_k<<<M_, 256, 0, stream>>>(attn);
    att_gemm_k<<<dim3((NANCH + BM - 1) / BM, D_ / BN, B_), 256, 0, stream>>>(attn, pf, att_feats);
    heads_gemm_k<<<dim3(M_ / BM, 2), 256, 0, stream>>>(att_feats, pf, cls_w, cls_b,
                                                       reg_w, reg_b, anchors, cls_out, lanes);
    lanes_init_k<<<(M_ * 4 + 255) / 256, 256, 0, stream>>>(anchors, lanes);
}

// Round 2
// 982.927 us; speedup vs baseline: 2.7452x; 2.7452x over previous
//
#include <hip/hip_runtime.h>

typedef unsigned short ushort_t;
typedef unsigned int   uint32;
typedef __attribute__((ext_vector_type(8))) short short8;   // 8 bf16 (4 VGPRs)
typedef __attribute__((ext_vector_type(4))) float f32x4;    // MFMA acc

// ---------------- problem constants ----------------
#define B_     8
#define CIN    512
#define HFM    10
#define WFM    25
#define CF     64
#define NANCH  2784          // N
#define NM     2783          // N-1
#define NMPAD  2816          // N-1 padded to 128
#define D_     640           // CF*HFM
#define D2     1280
#define ALEN   77
#define M_     (B_*NANCH)    // 22272

__device__ __forceinline__ ushort_t f2bf(float f) {
    uint32 u = __float_as_uint(f);
    u += 0x7fffu + ((u >> 16) & 1u);     // RNE
    return (ushort_t)(u >> 16);
}

__device__ __forceinline__ void gload16(const ushort_t* g, ushort_t* l) {
    __builtin_amdgcn_global_load_lds(
        (const __attribute__((address_space(1))) void*)g,
        (__attribute__((address_space(3))) void*)l, 16, 0, 0);
}

// ============ 1x1 conv ============
__global__ __launch_bounds__(256) void conv_feat_k(const float* __restrict__ x,
    const float* __restrict__ w, const float* __restrict__ bias,
    float* __restrict__ feat)
{
    int t = blockIdx.x * 256 + threadIdx.x;
    if (t >= B_ * CF * HFM * WFM) return;
    int pos = t % (HFM * WFM);
    int f   = (t / (HFM * WFM)) % CF;
    int b   = t / (CF * HFM * WFM);
    const float* xp = x + (size_t)b * CIN * HFM * WFM + pos;
    const float* wp = w + (size_t)f * CIN;
    float s = bias[f];
#pragma unroll 4
    for (int c = 0; c < CIN; ++c)
        s += xp[(size_t)c * (HFM * WFM)] * wp[c];
    feat[t] = s;
}

// ============ gather -> pf16 [M_][640] (row-major, coalesced writes) ============
__global__ __launch_bounds__(256) void gather_pf_k(const float* __restrict__ feat,
    const int* __restrict__ cut_xs, const unsigned char* __restrict__ invalid,
    ushort_t* __restrict__ pf16)
{
    long long t = (long long)blockIdx.x * 256 + threadIdx.x;
    if (t >= (long long)M_ * D_) return;
    int d = (int)(t % D_);
    int r = (int)(t / D_);
    int n = r % NANCH;
    int b = r / NANCH;
    int f = d / HFM, h = d - f * HFM;
    int idx = n * HFM + h;
    float v = 0.f;
    if (!invalid[idx]) {
        int xs = cut_xs[idx];
        v = feat[((size_t)(b * CF + f) * HFM + h) * WFM + xs];
    }
    pf16[t] = f2bf(v);
}

// ============ gather -> pfT16 [B][640][2784] (coalesced writes over n) ============
__global__ __launch_bounds__(256) void gather_pfT_k(const float* __restrict__ feat,
    const int* __restrict__ cut_xs, const unsigned char* __restrict__ invalid,
    ushort_t* __restrict__ pfT16)
{
    long long t = (long long)blockIdx.x * 256 + threadIdx.x;
    if (t >= (long long)B_ * D_ * NANCH) return;
    int n = (int)(t % NANCH);
    int d = (int)((t / NANCH) % D_);
    int b = (int)(t / ((long long)D_ * NANCH));
    int f = d / HFM, h = d - f * HFM;
    int idx = n * HFM + h;
    float v = 0.f;
    if (!invalid[idx]) {
        int xs = cut_xs[idx];
        v = feat[((size_t)(b * CF + f) * HFM + h) * WFM + xs];
    }
    pfT16[t] = f2bf(v);
}

// ============ attn_w fp32 [2783][640] -> bf16 padded [2816][640] ============
__global__ __launch_bounds__(256) void prep_attn_w_k(const float* __restrict__ attn_w,
    ushort_t* __restrict__ w16)
{
    int t = blockIdx.x * 256 + threadIdx.x;
    if (t >= NMPAD * D_) return;
    int m = t / D_;
    w16[t] = (m < NM) ? f2bf(attn_w[(size_t)m * D_ + (t % D_)]) : (ushort_t)0;
}

// ============ heads weights -> bf16 padded [128][1280] (rows: 2 cls, 73 reg, pad) ============
__global__ __launch_bounds__(256) void prep_heads_w_k(const float* __restrict__ cls_w,
    const float* __restrict__ reg_w, ushort_t* __restrict__ w16)
{
    int t = blockIdx.x * 256 + threadIdx.x;
    if (t >= 128 * D2) return;
    int o = t / D2, k = t % D2;
    float v = 0.f;
    if (o < 2)       v = cls_w[(size_t)o * D2 + k];
    else if (o < 75) v = reg_w[(size_t)(o - 2) * D2 + k];
    w16[t] = (o < 75) ? f2bf(v) : (ushort_t)0;
}

// ============ scores MFMA: attn_raw[r][m+(m>=n)] = pf·attn_w^T + attn_b ============
__global__ __launch_bounds__(256) void scores_mfma_k(
    const ushort_t* __restrict__ A,   // pf16 [M_][640]
    const ushort_t* __restrict__ Bw,  // attnw16 [2816][640]
    const float* __restrict__ attn_b,
    float* __restrict__ attn)         // [M_][2784]
{
    __shared__ __align__(16) ushort_t As[128 * 32];
    __shared__ __align__(16) ushort_t Bs[128 * 32];
    const int t = threadIdx.x;
    const int wid = t >> 6, lane = t & 63;
    const int wrow = (wid & 1) * 64, wcol = (wid >> 1) * 64;
    const int row0 = blockIdx.x * 128, col0 = blockIdx.y * 128;
    const int srow = t >> 2, skoff = (t & 3) * 8;
    const ushort_t* ga = A  + (size_t)(row0 + srow) * D_ + skoff;
    const ushort_t* gb = Bw + (size_t)(col0 + srow) * D_ + skoff;
    ushort_t* la = &As[wid * 512];
    ushort_t* lb = &Bs[wid * 512];
    f32x4 acc[4][4];
#pragma unroll
    for (int i = 0; i < 4; ++i)
#pragma unroll
        for (int j = 0; j < 4; ++j) acc[i][j] = (f32x4){0.f, 0.f, 0.f, 0.f};
    const int cl = lane & 15, q = lane >> 4;
    const int aoff = (wrow + cl) * 32 + q * 8;
    const int boff = (wcol + cl) * 32 + q * 8;

    for (int k0 = 0; k0 < D_; k0 += 32) {
        gload16(ga + k0, la);
        gload16(ga + k0 + (size_t)64 * D_, la + 2048);
        gload16(gb + k0, lb);
        gload16(gb + k0 + (size_t)64 * D_, lb + 2048);
        __syncthreads();
        short8 af[4], bf[4];
#pragma unroll
        for (int i = 0; i < 4; ++i) af[i] = *(const short8*)&As[aoff + i * 512];
#pragma unroll
        for (int j = 0; j < 4; ++j) bf[j] = *(const short8*)&Bs[boff + j * 512];
#pragma unroll
        for (int i = 0; i < 4; ++i)
#pragma unroll
            for (int j = 0; j < 4; ++j)
                acc[i][j] = __builtin_amdgcn_mfma_f32_16x16x32_bf16(af[i], bf[j], acc[i][j], 0, 0, 0);
        __syncthreads();
    }
#pragma unroll
    for (int i = 0; i < 4; ++i) {
#pragma unroll
        for (int e = 0; e < 4; ++e) {
            int r = row0 + wrow + i * 16 + q * 4 + e;
            int n = r % NANCH;
            float* orow = attn + (size_t)r * NANCH;
#pragma unroll
            for (int j = 0; j < 4; ++j) {
                int m = col0 + wcol + j * 16 + cl;
                if (m < NM) orow[m + (m >= n)] = acc[i][j][e] + attn_b[m];
            }
        }
    }
}

// ============ softmax per row (diagonal -> 0) ============
__global__ __launch_bounds__(256) void softmax_k(float* __restrict__ attn)
{
    const int r = blockIdx.x;
    const int n = r % NANCH;
    float* row = attn + (size_t)r * NANCH;
    const int t = threadIdx.x;
    __shared__ float red[4];
    float vals[11];
    int cnt = 0;
    float mx = -1e30f;
    for (int j = t; j < NANCH; j += 256) {
        float v = (j == n) ? -1e30f : row[j];
        vals[cnt++] = v;
        mx = fmaxf(mx, v);
    }
    for (int off = 32; off; off >>= 1) mx = fmaxf(mx, __shfl_down(mx, off));
    if ((t & 63) == 0) red[t >> 6] = mx;
    __syncthreads();
    mx = fmaxf(fmaxf(red[0], red[1]), fmaxf(red[2], red[3]));
    __syncthreads();
    float s = 0.f;
    for (int i = 0; i < cnt; ++i) {
        float e = __expf(vals[i] - mx);
        vals[i] = e;
        s += e;
    }
    for (int off = 32; off; off >>= 1) s += __shfl_down(s, off);
    if ((t & 63) == 0) red[t >> 6] = s;
    __syncthreads();
    s = red[0] + red[1] + red[2] + red[3];
    float inv = 1.0f / s;
    cnt = 0;
    for (int j = t; j < NANCH; j += 256)
        row[j] = vals[cnt++] * inv;
}

// ============ att MFMA: att16[b][n][d] = sum_j attn[b][n][j] * pfT[b][d][j] ============
__global__ __launch_bounds__(256) void att_mfma_k(
    const float* __restrict__ attn,    // [B][2784][2784] fp32
    const ushort_t* __restrict__ Bt,   // pfT16 [B][640][2784]
    ushort_t* __restrict__ att16)      // [B][2784][640]
{
    __shared__ __align__(16) ushort_t As[128 * 32];
    __shared__ __align__(16) ushort_t Bs[128 * 32];
    const int t = threadIdx.x;
    const int wid = t >> 6, lane = t & 63;
    const int wrow = (wid & 1) * 64, wcol = (wid >> 1) * 64;
    const int b = blockIdx.z;
    const int row0 = blockIdx.x * 128, col0 = blockIdx.y * 128;
    // A staging: fp32 -> bf16 manual. thread: rowA = t>>1 (0..127), koff = (t&1)*16
    const int rowA = t >> 1, koff = (t & 1) * 16;
    const int growA = row0 + rowA;
    const bool aval = (growA < NANCH);
    const float* gaRow = attn + ((size_t)b * NANCH + (aval ? growA : 0)) * NANCH + koff;
    // B staging via global_load_lds
    const int srow = t >> 2, skoff = (t & 3) * 8;
    const ushort_t* gb = Bt + ((size_t)b * D_ + col0 + srow) * NANCH + skoff;
    ushort_t* lb = &Bs[wid * 512];
    f32x4 acc[4][4];
#pragma unroll
    for (int i = 0; i < 4; ++i)
#pragma unroll
        for (int j = 0; j < 4; ++j) acc[i][j] = (f32x4){0.f, 0.f, 0.f, 0.f};
    const int cl = lane & 15, q = lane >> 4;
    const int aoff = (wrow + cl) * 32 + q * 8;
    const int boff = (wcol + cl) * 32 + q * 8;

    for (int k0 = 0; k0 < NANCH; k0 += 32) {
        gload16(gb + k0, lb);
        gload16(gb + k0 + (size_t)64 * NANCH, lb + 2048);
        float4 f0 = make_float4(0.f, 0.f, 0.f, 0.f), f1 = f0, f2 = f0, f3 = f0;
        if (aval) {
            f0 = *(const float4*)(gaRow + k0);
            f1 = *(const float4*)(gaRow + k0 + 4);
            f2 = *(const float4*)(gaRow + k0 + 8);
            f3 = *(const float4*)(gaRow + k0 + 12);
        }
        uint32 p[8];
        p[0] = (uint32)f2bf(f0.x) | ((uint32)f2bf(f0.y) << 16);
        p[1] = (uint32)f2bf(f0.z) | ((uint32)f2bf(f0.w) << 16);
        p[2] = (uint32)f2bf(f1.x) | ((uint32)f2bf(f1.y) << 16);
        p[3] = (uint32)f2bf(f1.z) | ((uint32)f2bf(f1.w) << 16);
        p[4] = (uint32)f2bf(f2.x) | ((uint32)f2bf(f2.y) << 16);
        p[5] = (uint32)f2bf(f2.z) | ((uint32)f2bf(f2.w) << 16);
        p[6] = (uint32)f2bf(f3.x) | ((uint32)f2bf(f3.y) << 16);
        p[7] = (uint32)f2bf(f3.z) | ((uint32)f2bf(f3.w) << 16);
        uint32* dst = (uint32*)&As[rowA * 32 + koff];
        *(uint4*)(dst + 0) = make_uint4(p[0], p[1], p[2], p[3]);
        *(uint4*)(dst + 4) = make_uint4(p[4], p[5], p[6], p[7]);
        __syncthreads();
        short8 af[4], bf[4];
#pragma unroll
        for (int i = 0; i < 4; ++i) af[i] = *(const short8*)&As[aoff + i * 512];
#pragma unroll
        for (int j = 0; j < 4; ++j) bf[j] = *(const short8*)&Bs[boff + j * 512];
#pragma unroll
        for (int i = 0; i < 4; ++i)
#pragma unroll
            for (int j = 0; j < 4; ++j)
                acc[i][j] = __builtin_amdgcn_mfma_f32_16x16x32_bf16(af[i], bf[j], acc[i][j], 0, 0, 0);
        __syncthreads();
    }
#pragma unroll
    for (int i = 0; i < 4; ++i) {
#pragma unroll
        for (int e = 0; e < 4; ++e) {
            int row = row0 + wrow + i * 16 + q * 4 + e;
            if (row < NANCH) {
                ushort_t* orow = att16 + ((size_t)b * NANCH + row) * D_;
#pragma unroll
                for (int j = 0; j < 4; ++j) {
                    int d = col0 + wcol + j * 16 + cl;
                    orow[d] = f2bf(acc[i][j][e]);
                }
            }
        }
    }
}

// ============ heads MFMA: [cls|reg] = [att16|pf16]·W^T, fused lanes epilogue ============
__global__ __launch_bounds__(256) void heads_mfma_k(
    const ushort_t* __restrict__ att16, const ushort_t* __restrict__ pf16,
    const ushort_t* __restrict__ W,    // [128][1280] bf16 padded
    const float* __restrict__ cls_b, const float* __restrict__ reg_b,
    const float* __restrict__ anchors,
    float* __restrict__ cls_out, float* __restrict__ lanes)
{
    __shared__ __align__(16) ushort_t As[128 * 32];
    __shared__ __align__(16) ushort_t Bs[128 * 32];
    const int t = threadIdx.x;
    const int wid = t >> 6, lane = t & 63;
    const int wrow = (wid & 1) * 64, wcol = (wid >> 1) * 64;
    const int row0 = blockIdx.x * 128;
    const int srow = t >> 2, skoff = (t & 3) * 8;
    const ushort_t* gw = W + (size_t)srow * D2 + skoff;
    ushort_t* la = &As[wid * 512];
    ushort_t* lb = &Bs[wid * 512];
    f32x4 acc[4][4];
#pragma unroll
    for (int i = 0; i < 4; ++i)
#pragma unroll
        for (int j = 0; j < 4; ++j) acc[i][j] = (f32x4){0.f, 0.f, 0.f, 0.f};
    const int cl = lane & 15, q = lane >> 4;
    const int aoff = (wrow + cl) * 32 + q * 8;
    const int boff = (wcol + cl) * 32 + q * 8;

    for (int k0 = 0; k0 < D2; k0 += 32) {
        const ushort_t* ga = (k0 < D_)
            ? att16 + (size_t)(row0 + srow) * D_ + k0 + skoff
            : pf16  + (size_t)(row0 + srow) * D_ + (k0 - D_) + skoff;
        gload16(ga, la);
        gload16(ga + (size_t)64 * D_, la + 2048);
        gload16(gw + k0, lb);
        gload16(gw + k0 + (size_t)64 * D2, lb + 2048);
        __syncthreads();
        short8 af[4], bf[4];
#pragma unroll
        for (int i = 0; i < 4; ++i) af[i] = *(const short8*)&As[aoff + i * 512];
#pragma unroll
        for (int j = 0; j < 4; ++j) bf[j] = *(const short8*)&Bs[boff + j * 512];
#pragma unroll
        for (int i = 0; i < 4; ++i)
#pragma unroll
            for (int j = 0; j < 4; ++j)
                acc[i][j] = __builtin_amdgcn_mfma_f32_16x16x32_bf16(af[i], bf[j], acc[i][j], 0, 0, 0);
        __syncthreads();
    }
#pragma unroll
    for (int i = 0; i < 4; ++i) {
#pragma unroll
        for (int e = 0; e < 4; ++e) {
            int r = row0 + wrow + i * 16 + q * 4 + e;
            int n = r % NANCH;
#pragma unroll
            for (int j = 0; j < 4; ++j) {
                int oo = wcol + j * 16 + cl;
                float v = acc[i][j][e];
                if (oo < 2) {
                    cls_out[(size_t)r * 2 + oo] = v + cls_b[oo];
                } else if (oo < 75) {
                    int qq = oo - 2;
                    int c = 4 + qq;
                    float res = v + reg_b[qq];
                    if (qq > 0) res += anchors[(size_t)n * ALEN + c];
                    lanes[(size_t)r * ALEN + c] = res;
                }
            }
        }
    }
}

// ============ lanes cols 0..3 from anchors ============
__global__ __launch_bounds__(256) void lanes_init_k(const float* __restrict__ anchors,
    float* __restrict__ lanes)
{
    int t = blockIdx.x * 256 + threadIdx.x;
    if (t >= M_ * 4) return;
    int c = t & 3;
    int r = t >> 2;
    int n = r % NANCH;
    lanes[(size_t)r * ALEN + c] = anchors[(size_t)n * ALEN + c];
}

extern "C" void kernel_launch(void* const* d_in, const int* in_sizes, int n_in,
                              void* d_out, int out_size, void* d_ws, size_t ws_size,
                              hipStream_t stream)
{
    (void)in_sizes; (void)n_in; (void)out_size; (void)ws_size;
    const float* x       = (const float*)d_in[0];
    const float* conv_w  = (const float*)d_in[1];
    const float* conv_b  = (const float*)d_in[2];
    const float* attn_w  = (const float*)d_in[3];
    const float* attn_b  = (const float*)d_in[4];
    const float* cls_w   = (const float*)d_in[5];
    const float* cls_b   = (const float*)d_in[6];
    const float* reg_w   = (const float*)d_in[7];
    const float* reg_b   = (const float*)d_in[8];
    const float* anchors = (const float*)d_in[9];
    const int*   cut_xs  = (const int*)d_in[10];
    const unsigned char* invalid = (const unsigned char*)d_in[11];

    float* out     = (float*)d_out;
    float* cls_out = out;
    float* lanes   = out + (size_t)M_ * 2;
    float* attn    = out + (size_t)M_ * 2 + (size_t)M_ * ALEN;

    // workspace layout (~90 MB)
    char* w = (char*)d_ws;
    float* feat      = (float*)w;            w += (size_t)B_ * CF * HFM * WFM * 4;   // 512 KB
    ushort_t* pf16   = (ushort_t*)w;         w += (size_t)M_ * D_ * 2;               // 28.5 MB
    ushort_t* pfT16  = (ushort_t*)w;         w += (size_t)B_ * D_ * NANCH * 2;       // 28.5 MB
    ushort_t* aw16   = (ushort_t*)w;         w += (size_t)NMPAD * D_ * 2;            // 3.6 MB
    ushort_t* att16  = (ushort_t*)w;         w += (size_t)M_ * D_ * 2;               // 28.5 MB
    ushort_t* hw16   = (ushort_t*)w;         w += (size_t)128 * D2 * 2;              // 320 KB

    conv_feat_k<<<(B_ * CF * HFM * WFM + 255) / 256, 256, 0, stream>>>(x, conv_w, conv_b, feat);
    gather_pf_k<<<(int)(((long long)M_ * D_ + 255) / 256), 256, 0, stream>>>(feat, cut_xs, invalid, pf16);
    gather_pfT_k<<<(int)(((long long)B_ * D_ * NANCH + 255) / 256), 256, 0, stream>>>(feat, cut_xs, invalid, pfT16);
    prep_attn_w_k<<<(NMPAD * D_ + 255) / 256, 256, 0, stream>>>(attn_w, aw16);
    prep_heads_w_k<<<(128 * D2 + 255) / 256, 256, 0, stream>>>(cls_w, reg_w, hw16);

    scores_mfma_k<<<dim3(M_ / 128, NMPAD / 128), 256, 0, stream>>>(pf16, aw16, attn_b, attn);
    softmax_k<<<M_, 256, 0, stream>>>(attn);
    att_mfma_k<<<dim3((NANCH + 127) / 128, D_ / 128, B_), 256, 0, stream>>>(attn, pfT16, att16);
    heads_mfma_k<<<dim3(M_ / 128), 256, 0, stream>>>(att16, pf16, hw16, cls_b, reg_b, anchors, cls_out, lanes);
    lanes_init_k<<<(M_ * 4 + 255) / 256, 256, 0, stream>>>(anchors, lanes);
}

// Round 3
// 969.254 us; speedup vs baseline: 2.7840x; 1.0141x over previous
//
#include <hip/hip_runtime.h>

typedef unsigned short ushort_t;
typedef unsigned int   uint32;
typedef __attribute__((ext_vector_type(8))) short short8;   // 8 bf16 (4 VGPRs)
typedef __attribute__((ext_vector_type(4))) float f32x4;    // MFMA acc

// ---------------- problem constants ----------------
#define B_     8
#define CIN    512
#define HFM    10
#define WFM    25
#define CF     64
#define NANCH  2784          // N
#define NM     2783          // N-1
#define NMPAD  2816          // N-1 padded to 128
#define D_     640           // CF*HFM
#define D2     1280
#define ALEN   77
#define M_     (B_*NANCH)    // 22272

__device__ __forceinline__ ushort_t f2bf(float f) {
    uint32 u = __float_as_uint(f);
    u += 0x7fffu + ((u >> 16) & 1u);     // RNE
    return (ushort_t)(u >> 16);
}

__device__ __forceinline__ void gload16(const ushort_t* g, ushort_t* l) {
    __builtin_amdgcn_global_load_lds(
        (const __attribute__((address_space(1))) void*)g,
        (__attribute__((address_space(3))) void*)l, 16, 0, 0);
}

// ============ 1x1 conv ============
__global__ __launch_bounds__(256) void conv_feat_k(const float* __restrict__ x,
    const float* __restrict__ w, const float* __restrict__ bias,
    float* __restrict__ feat)
{
    int t = blockIdx.x * 256 + threadIdx.x;
    if (t >= B_ * CF * HFM * WFM) return;
    int pos = t % (HFM * WFM);
    int f   = (t / (HFM * WFM)) % CF;
    int b   = t / (CF * HFM * WFM);
    const float* xp = x + (size_t)b * CIN * HFM * WFM + pos;
    const float* wp = w + (size_t)f * CIN;
    float s = bias[f];
#pragma unroll 4
    for (int c = 0; c < CIN; ++c)
        s += xp[(size_t)c * (HFM * WFM)] * wp[c];
    feat[t] = s;
}

// ============ gather -> pf16 [M_][640] ============
__global__ __launch_bounds__(256) void gather_pf_k(const float* __restrict__ feat,
    const int* __restrict__ cut_xs, const unsigned char* __restrict__ invalid,
    ushort_t* __restrict__ pf16)
{
    long long t = (long long)blockIdx.x * 256 + threadIdx.x;
    if (t >= (long long)M_ * D_) return;
    int d = (int)(t % D_);
    int r = (int)(t / D_);
    int n = r % NANCH;
    int b = r / NANCH;
    int f = d / HFM, h = d - f * HFM;
    int idx = n * HFM + h;
    float v = 0.f;
    if (!invalid[idx]) {
        int xs = cut_xs[idx];
        v = feat[((size_t)(b * CF + f) * HFM + h) * WFM + xs];
    }
    pf16[t] = f2bf(v);
}

// ============ gather -> pfT16 [B][640][2784] ============
__global__ __launch_bounds__(256) void gather_pfT_k(const float* __restrict__ feat,
    const int* __restrict__ cut_xs, const unsigned char* __restrict__ invalid,
    ushort_t* __restrict__ pfT16)
{
    long long t = (long long)blockIdx.x * 256 + threadIdx.x;
    if (t >= (long long)B_ * D_ * NANCH) return;
    int n = (int)(t % NANCH);
    int d = (int)((t / NANCH) % D_);
    int b = (int)(t / ((long long)D_ * NANCH));
    int f = d / HFM, h = d - f * HFM;
    int idx = n * HFM + h;
    float v = 0.f;
    if (!invalid[idx]) {
        int xs = cut_xs[idx];
        v = feat[((size_t)(b * CF + f) * HFM + h) * WFM + xs];
    }
    pfT16[t] = f2bf(v);
}

// ============ attn_w fp32 [2783][640] -> bf16 padded [2816][640] ============
__global__ __launch_bounds__(256) void prep_attn_w_k(const float* __restrict__ attn_w,
    ushort_t* __restrict__ w16)
{
    int t = blockIdx.x * 256 + threadIdx.x;
    if (t >= NMPAD * D_) return;
    int m = t / D_;
    w16[t] = (m < NM) ? f2bf(attn_w[(size_t)m * D_ + (t % D_)]) : (ushort_t)0;
}

// ============ heads weights -> bf16 padded [128][1280] ============
__global__ __launch_bounds__(256) void prep_heads_w_k(const float* __restrict__ cls_w,
    const float* __restrict__ reg_w, ushort_t* __restrict__ w16)
{
    int t = blockIdx.x * 256 + threadIdx.x;
    if (t >= 128 * D2) return;
    int o = t / D2, k = t % D2;
    float v = 0.f;
    if (o < 2)       v = cls_w[(size_t)o * D2 + k];
    else if (o < 75) v = reg_w[(size_t)(o - 2) * D2 + k];
    w16[t] = (o < 75) ? f2bf(v) : (ushort_t)0;
}

// ============ scores MFMA: attn_raw[r][m+(m>=n)] = pf·attn_w^T + attn_b ============
__global__ __launch_bounds__(256) void scores_mfma_k(
    const ushort_t* __restrict__ A,   // pf16 [M_][640]
    const ushort_t* __restrict__ Bw,  // attnw16 [2816][640]
    const float* __restrict__ attn_b,
    float* __restrict__ attn)         // [M_][2784]
{
    __shared__ __align__(16) ushort_t As[128 * 32];
    __shared__ __align__(16) ushort_t Bs[128 * 32];
    const int t = threadIdx.x;
    const int wid = t >> 6, lane = t & 63;
    const int wrow = (wid & 1) * 64, wcol = (wid >> 1) * 64;
    const int row0 = blockIdx.x * 128, col0 = blockIdx.y * 128;
    const int srow = t >> 2, skoff = (t & 3) * 8;
    const ushort_t* ga = A  + (size_t)(row0 + srow) * D_ + skoff;
    const ushort_t* gb = Bw + (size_t)(col0 + srow) * D_ + skoff;
    ushort_t* la = &As[wid * 512];
    ushort_t* lb = &Bs[wid * 512];
    f32x4 acc[4][4];
#pragma unroll
    for (int i = 0; i < 4; ++i)
#pragma unroll
        for (int j = 0; j < 4; ++j) acc[i][j] = (f32x4){0.f, 0.f, 0.f, 0.f};
    const int cl = lane & 15, q = lane >> 4;
    const int aoff = (wrow + cl) * 32 + q * 8;
    const int boff = (wcol + cl) * 32 + q * 8;

    for (int k0 = 0; k0 < D_; k0 += 32) {
        gload16(ga + k0, la);
        gload16(ga + k0 + (size_t)64 * D_, la + 2048);
        gload16(gb + k0, lb);
        gload16(gb + k0 + (size_t)64 * D_, lb + 2048);
        __syncthreads();
        short8 af[4], bf[4];
#pragma unroll
        for (int i = 0; i < 4; ++i) af[i] = *(const short8*)&As[aoff + i * 512];
#pragma unroll
        for (int j = 0; j < 4; ++j) bf[j] = *(const short8*)&Bs[boff + j * 512];
#pragma unroll
        for (int i = 0; i < 4; ++i)
#pragma unroll
            for (int j = 0; j < 4; ++j)
                acc[i][j] = __builtin_amdgcn_mfma_f32_16x16x32_bf16(af[i], bf[j], acc[i][j], 0, 0, 0);
        __syncthreads();
    }
#pragma unroll
    for (int i = 0; i < 4; ++i) {
#pragma unroll
        for (int e = 0; e < 4; ++e) {
            int r = row0 + wrow + i * 16 + q * 4 + e;
            int n = r % NANCH;
            float* orow = attn + (size_t)r * NANCH;
#pragma unroll
            for (int j = 0; j < 4; ++j) {
                int m = col0 + wcol + j * 16 + cl;
                if (m < NM) orow[m + (m >= n)] = acc[i][j][e] + attn_b[m];
            }
        }
    }
}

// ============ softmax per row (diagonal -> 0); fp32 to d_out, bf16 copy to ws ============
__global__ __launch_bounds__(256) void softmax_k(float* __restrict__ attn,
    ushort_t* __restrict__ attn16)
{
    const int r = blockIdx.x;
    const int n = r % NANCH;
    float* row = attn + (size_t)r * NANCH;
    ushort_t* row16 = attn16 + (size_t)r * NANCH;
    const int t = threadIdx.x;
    __shared__ float red[4];
    float vals[11];
    int cnt = 0;
    float mx = -1e30f;
    for (int j = t; j < NANCH; j += 256) {
        float v = (j == n) ? -1e30f : row[j];
        vals[cnt++] = v;
        mx = fmaxf(mx, v);
    }
    for (int off = 32; off; off >>= 1) mx = fmaxf(mx, __shfl_down(mx, off));
    if ((t & 63) == 0) red[t >> 6] = mx;
    __syncthreads();
    mx = fmaxf(fmaxf(red[0], red[1]), fmaxf(red[2], red[3]));
    __syncthreads();
    float s = 0.f;
    for (int i = 0; i < cnt; ++i) {
        float e = __expf(vals[i] - mx);
        vals[i] = e;
        s += e;
    }
    for (int off = 32; off; off >>= 1) s += __shfl_down(s, off);
    if ((t & 63) == 0) red[t >> 6] = s;
    __syncthreads();
    s = red[0] + red[1] + red[2] + red[3];
    float inv = 1.0f / s;
    cnt = 0;
    for (int j = t; j < NANCH; j += 256) {
        float v = vals[cnt++] * inv;       // diagonal: 0
        row[j] = v;
        row16[j] = f2bf(v);
    }
}

// ============ att MFMA (pure bf16): att16[b][n][d] = attn16[b][n][:]·pfT[b][d][:] ============
__global__ __launch_bounds__(256) void att_mfma_k(
    const ushort_t* __restrict__ A16,  // attn16 [M_+32][2784]
    const ushort_t* __restrict__ Bt,   // pfT16 [B][640][2784]
    ushort_t* __restrict__ att16)      // [B][2784][640]
{
    __shared__ __align__(16) ushort_t As[128 * 32];
    __shared__ __align__(16) ushort_t Bs[128 * 32];
    const int t = threadIdx.x;
    const int wid = t >> 6, lane = t & 63;
    const int wrow = (wid & 1) * 64, wcol = (wid >> 1) * 64;
    const int b = blockIdx.z;
    const int row0 = blockIdx.x * 128, col0 = blockIdx.y * 128;
    const int srow = t >> 2, skoff = (t & 3) * 8;
    // A rows may over-read past batch end (padded +32 rows at buffer end); results discarded.
    const ushort_t* ga = A16 + ((size_t)b * NANCH + row0 + srow) * NANCH + skoff;
    const ushort_t* gb = Bt  + ((size_t)b * D_ + col0 + srow) * NANCH + skoff;
    ushort_t* la = &As[wid * 512];
    ushort_t* lb = &Bs[wid * 512];
    f32x4 acc[4][4];
#pragma unroll
    for (int i = 0; i < 4; ++i)
#pragma unroll
        for (int j = 0; j < 4; ++j) acc[i][j] = (f32x4){0.f, 0.f, 0.f, 0.f};
    const int cl = lane & 15, q = lane >> 4;
    const int aoff = (wrow + cl) * 32 + q * 8;
    const int boff = (wcol + cl) * 32 + q * 8;

    for (int k0 = 0; k0 < NANCH; k0 += 32) {
        gload16(ga + k0, la);
        gload16(ga + k0 + (size_t)64 * NANCH, la + 2048);
        gload16(gb + k0, lb);
        gload16(gb + k0 + (size_t)64 * NANCH, lb + 2048);
        __syncthreads();
        short8 af[4], bf[4];
#pragma unroll
        for (int i = 0; i < 4; ++i) af[i] = *(const short8*)&As[aoff + i * 512];
#pragma unroll
        for (int j = 0; j < 4; ++j) bf[j] = *(const short8*)&Bs[boff + j * 512];
#pragma unroll
        for (int i = 0; i < 4; ++i)
#pragma unroll
            for (int j = 0; j < 4; ++j)
                acc[i][j] = __builtin_amdgcn_mfma_f32_16x16x32_bf16(af[i], bf[j], acc[i][j], 0, 0, 0);
        __syncthreads();
    }
#pragma unroll
    for (int i = 0; i < 4; ++i) {
#pragma unroll
        for (int e = 0; e < 4; ++e) {
            int row = row0 + wrow + i * 16 + q * 4 + e;
            if (row < NANCH) {
                ushort_t* orow = att16 + ((size_t)b * NANCH + row) * D_;
#pragma unroll
                for (int j = 0; j < 4; ++j) {
                    int d = col0 + wcol + j * 16 + cl;
                    orow[d] = f2bf(acc[i][j][e]);
                }
            }
        }
    }
}

// ============ heads MFMA: [cls|reg] = [att16|pf16]·W^T; fused lanes epilogue + lanes cols 0..3 ============
__global__ __launch_bounds__(256) void heads_mfma_k(
    const ushort_t* __restrict__ att16, const ushort_t* __restrict__ pf16,
    const ushort_t* __restrict__ W,    // [128][1280] bf16 padded
    const float* __restrict__ cls_b, const float* __restrict__ reg_b,
    const float* __restrict__ anchors,
    float* __restrict__ cls_out, float* __restrict__ lanes)
{
    __shared__ __align__(16) ushort_t As[128 * 32];
    __shared__ __align__(16) ushort_t Bs[128 * 32];
    const int t = threadIdx.x;
    const int wid = t >> 6, lane = t & 63;
    const int wrow = (wid & 1) * 64, wcol = (wid >> 1) * 64;
    const int row0 = blockIdx.x * 128;
    const int srow = t >> 2, skoff = (t & 3) * 8;
    const ushort_t* gw = W + (size_t)srow * D2 + skoff;
    ushort_t* la = &As[wid * 512];
    ushort_t* lb = &Bs[wid * 512];
    f32x4 acc[4][4];
#pragma unroll
    for (int i = 0; i < 4; ++i)
#pragma unroll
        for (int j = 0; j < 4; ++j) acc[i][j] = (f32x4){0.f, 0.f, 0.f, 0.f};
    const int cl = lane & 15, q = lane >> 4;
    const int aoff = (wrow + cl) * 32 + q * 8;
    const int boff = (wcol + cl) * 32 + q * 8;

    for (int k0 = 0; k0 < D2; k0 += 32) {
        const ushort_t* ga = (k0 < D_)
            ? att16 + (size_t)(row0 + srow) * D_ + k0 + skoff
            : pf16  + (size_t)(row0 + srow) * D_ + (k0 - D_) + skoff;
        gload16(ga, la);
        gload16(ga + (size_t)64 * D_, la + 2048);
        gload16(gw + k0, lb);
        gload16(gw + k0 + (size_t)64 * D2, lb + 2048);
        __syncthreads();
        short8 af[4], bf[4];
#pragma unroll
        for (int i = 0; i < 4; ++i) af[i] = *(const short8*)&As[aoff + i * 512];
#pragma unroll
        for (int j = 0; j < 4; ++j) bf[j] = *(const short8*)&Bs[boff + j * 512];
#pragma unroll
        for (int i = 0; i < 4; ++i)
#pragma unroll
            for (int j = 0; j < 4; ++j)
                acc[i][j] = __builtin_amdgcn_mfma_f32_16x16x32_bf16(af[i], bf[j], acc[i][j], 0, 0, 0);
        __syncthreads();
    }
#pragma unroll
    for (int i = 0; i < 4; ++i) {
#pragma unroll
        for (int e = 0; e < 4; ++e) {
            int r = row0 + wrow + i * 16 + q * 4 + e;
            int n = r % NANCH;
#pragma unroll
            for (int j = 0; j < 4; ++j) {
                int oo = wcol + j * 16 + cl;
                float v = acc[i][j][e];
                if (oo < 2) {
                    cls_out[(size_t)r * 2 + oo] = v + cls_b[oo];
                } else if (oo < 75) {
                    int qq = oo - 2;
                    int c = 4 + qq;
                    float res = v + reg_b[qq];
                    if (qq > 0) res += anchors[(size_t)n * ALEN + c];
                    lanes[(size_t)r * ALEN + c] = res;
                } else if (oo < 79) {
                    int c = oo - 75;                      // lanes cols 0..3 = anchors
                    lanes[(size_t)r * ALEN + c] = anchors[(size_t)n * ALEN + c];
                }
            }
        }
    }
}

extern "C" void kernel_launch(void* const* d_in, const int* in_sizes, int n_in,
                              void* d_out, int out_size, void* d_ws, size_t ws_size,
                              hipStream_t stream)
{
    (void)in_sizes; (void)n_in; (void)out_size; (void)ws_size;
    const float* x       = (const float*)d_in[0];
    const float* conv_w  = (const float*)d_in[1];
    const float* conv_b  = (const float*)d_in[2];
    const float* attn_w  = (const float*)d_in[3];
    const float* attn_b  = (const float*)d_in[4];
    const float* cls_w   = (const float*)d_in[5];
    const float* cls_b   = (const float*)d_in[6];
    const float* reg_w   = (const float*)d_in[7];
    const float* reg_b   = (const float*)d_in[8];
    const float* anchors = (const float*)d_in[9];
    const int*   cut_xs  = (const int*)d_in[10];
    const unsigned char* invalid = (const unsigned char*)d_in[11];

    float* out     = (float*)d_out;
    float* cls_out = out;
    float* lanes   = out + (size_t)M_ * 2;
    float* attn    = out + (size_t)M_ * 2 + (size_t)M_ * ALEN;

    // workspace layout (~215 MB)
    char* w = (char*)d_ws;
    float* feat      = (float*)w;    w += (size_t)B_ * CF * HFM * WFM * 4;       // 512 KB
    ushort_t* pf16   = (ushort_t*)w; w += (size_t)M_ * D_ * 2;                   // 28.5 MB
    ushort_t* pfT16  = (ushort_t*)w; w += (size_t)B_ * D_ * NANCH * 2;           // 28.5 MB
    ushort_t* aw16   = (ushort_t*)w; w += (size_t)NMPAD * D_ * 2;                // 3.6 MB
    ushort_t* att16  = (ushort_t*)w; w += (size_t)M_ * D_ * 2;                   // 28.5 MB
    ushort_t* hw16   = (ushort_t*)w; w += (size_t)128 * D2 * 2;                  // 320 KB
    ushort_t* attn16 = (ushort_t*)w; w += (size_t)(M_ + 32) * NANCH * 2;         // 124.2 MB (+32-row pad)

    conv_feat_k<<<(B_ * CF * HFM * WFM + 255) / 256, 256, 0, stream>>>(x, conv_w, conv_b, feat);
    gather_pf_k<<<(int)(((long long)M_ * D_ + 255) / 256), 256, 0, stream>>>(feat, cut_xs, invalid, pf16);
    gather_pfT_k<<<(int)(((long long)B_ * D_ * NANCH + 255) / 256), 256, 0, stream>>>(feat, cut_xs, invalid, pfT16);
    prep_attn_w_k<<<(NMPAD * D_ + 255) / 256, 256, 0, stream>>>(attn_w, aw16);
    prep_heads_w_k<<<(128 * D2 + 255) / 256, 256, 0, stream>>>(cls_w, reg_w, hw16);

    scores_mfma_k<<<dim3(M_ / 128, NMPAD / 128), 256, 0, stream>>>(pf16, aw16, attn_b, attn);
    softmax_k<<<M_, 256, 0, stream>>>(attn, attn16);
    att_mfma_k<<<dim3((NANCH + 127) / 128, D_ / 128, B_), 256, 0, stream>>>(attn16, pfT16, att16);
    heads_mfma_k<<<dim3(M_ / 128), 256, 0, stream>>>(att16, pf16, hw16, cls_b, reg_b, anchors, cls_out, lanes);
}